// Round 4
// baseline (223.497 us; speedup 1.0000x reference)
//
#include <hip/hip_runtime.h>

// Batched Kalman step: G groups, S=16, M=8, fp32. One wave per group,
// 4 waves/block, wave-private LDS (no __syncthreads; same-wave DS is in-order).
//
// R4: coalesced first-touch staging (cov/F/H via lane*4 float4 -> LDS),
// LDS region reuse => 5120 B/wave = 20480 B/block => 8 blocks/CU (32 waves).
// 2x2-blocked in-register Gauss-Jordan (4 serial stages, not 8).
// pred_cov written as coalesced float4 via symmetry.

#define WSYNC() asm volatile("" ::: "memory")

__device__ __forceinline__ float lane_bcast(float v, int srclane) {
    return __int_as_float(__builtin_amdgcn_readlane(__float_as_int(v), srclane));
}
__device__ __forceinline__ float dot4(float4 a, float4 b) {
    return a.x*b.x + a.y*b.y + a.z*b.z + a.w*b.w;
}

__global__ __launch_bounds__(256, 8) void kalman_kernel(
    const float* __restrict__ g_in,
    const float* __restrict__ g_mean,
    const float* __restrict__ g_cov,
    const float* __restrict__ g_H,
    const float* __restrict__ g_R,
    const float* __restrict__ g_F,
    const float* __restrict__ g_Q,
    float* __restrict__ g_out,
    int G)
{
    // per-wave LDS layout (floats), 1280 total = 5120 B:
    //  sCov[16][20]@0    -> reused as sNC after step 1
    //  sF  [16][20]@320
    //  sCT [8][20] @640  -> (with sCTT) reused as sT3 after NC
    //  sCTT[16][12]@800
    //  sX  [8][16] @992  -> head reused as sNM after NC reads it
    //  sH  [8][20] @1120
    __shared__ __align__(16) float smem[4][1280];
    const int wv   = threadIdx.x >> 6;
    const int lane = threadIdx.x & 63;
    const int g    = (blockIdx.x << 2) | wv;
    float* const sm   = smem[wv];
    float* const sCov = sm;
    float* const sNC  = sm;
    float* const sF   = sm + 320;
    float* const sCT  = sm + 640;
    float* const sT3  = sm + 640;
    float* const sCTT = sm + 800;
    float* const sX   = sm + 992;
    float* const sNM  = sm + 992;
    float* const sH   = sm + 1120;

    const int r  = lane >> 2;        // 0..15
    const int c0 = (lane & 3) << 2;  // 0,4,8,12
    const int gi = lane >> 3;        // 0..7
    const int gj = lane & 7;         // 0..7

    // ---- stage (coalesced first-touch: contiguous lane*4 float4 loads) ----
    const float4 cv = *reinterpret_cast<const float4*>(g_cov + (size_t)g*256 + lane*4);
    const float4 fv = *reinterpret_cast<const float4*>(g_F   + (size_t)g*256 + lane*4);
    *reinterpret_cast<float4*>(sCov + r*20 + c0) = cv;
    *reinterpret_cast<float4*>(sF   + r*20 + c0) = fv;
    if (lane < 32) {
        const float4 hv = *reinterpret_cast<const float4*>(g_H + (size_t)g*128 + lane*4);
        *reinterpret_cast<float4*>(sH + (lane>>2)*20 + ((lane&3)<<2)) = hv;
    }
    WSYNC();

    // ---- H row gi -> registers (CT, Ssys, resid all use it) ----
    float4 hq[4];
    #pragma unroll
    for (int q = 0; q < 4; ++q)
        hq[q] = *reinterpret_cast<const float4*>(sH + gi*20 + 4*q);

    // ---- 1: CT = H@cov (cov sym): lane (gi,gj) -> CT[gi][gj], CT[gi][gj+8]
    //         (conflict-free row reads; b0/b1 for the solve stay local) ----
    float b0 = 0.f, b1 = 0.f;
    {
        #pragma unroll
        for (int q = 0; q < 4; ++q) {
            const float4 ca = *reinterpret_cast<const float4*>(sCov + gj*20 + 4*q);
            const float4 cb = *reinterpret_cast<const float4*>(sCov + (gj+8)*20 + 4*q);
            b0 += dot4(hq[q], ca);
            b1 += dot4(hq[q], cb);
        }
        sCT[gi*20 + gj]     = b0;
        sCT[gi*20 + gj + 8] = b1;
        sCTT[gj*12 + gi]       = b0;   // CT^T rows for the NC step
        sCTT[(gj+8)*12 + gi]   = b1;
    }
    WSYNC();

    // ---- 2: a = Ssys[gi][gj] = R[gi][gj] + dot(H row gi, CT row gj); resid ----
    float a = g_R[(size_t)g*64 + gi*8 + gj];
    #pragma unroll
    for (int q = 0; q < 4; ++q) {
        const float4 ct = *reinterpret_cast<const float4*>(sCT + gj*20 + 4*q);
        a += dot4(hq[q], ct);
    }
    float rin = g_in[(size_t)g*8 + gi];
    #pragma unroll
    for (int q = 0; q < 4; ++q) {
        const float4 m4 = *reinterpret_cast<const float4*>(g_mean + (size_t)g*16 + 4*q);
        rin -= dot4(hq[q], m4);
    }

    // ---- 3: 2x2-blocked Gauss-Jordan: [Ssys | CT] -> X = Ssys^-1 CT ----
    // 4 serial stages (half the bpermute-latency chain of scalar GJ).
    // SPD => leading 2x2 pivot blocks of successive Schur complements invertible.
    #pragma unroll
    for (int k = 0; k < 8; k += 2) {
        const int rk = k << 3, rk1 = (k+1) << 3;
        const float rka   = __shfl(a,  rk  | gj);
        const float rk1a  = __shfl(a,  rk1 | gj);
        const float rkb0  = __shfl(b0, rk  | gj);
        const float rk1b0 = __shfl(b0, rk1 | gj);
        const float rkb1  = __shfl(b1, rk  | gj);
        const float rk1b1 = __shfl(b1, rk1 | gj);
        const float ai0   = __shfl(a, (gi << 3) | k);
        const float ai1   = __shfl(a, (gi << 3) | (k+1));
        const float p00 = lane_bcast(a, rk  | k);
        const float p01 = lane_bcast(a, rk  | (k+1));
        const float p10 = lane_bcast(a, rk1 | k);
        const float p11 = lane_bcast(a, rk1 | (k+1));
        const float det  = p00*p11 - p01*p10;
        const float rdet = __builtin_amdgcn_rcpf(det);
        const float i00 =  p11*rdet, i01 = -p01*rdet;
        const float i10 = -p10*rdet, i11 =  p00*rdet;
        const float c0_ = ai0*i00 + ai1*i10;
        const float c1_ = ai0*i01 + ai1*i11;
        float na, nb0, nb1;
        if (gi == k) {
            na  = i00*rka  + i01*rk1a;
            nb0 = i00*rkb0 + i01*rk1b0;
            nb1 = i00*rkb1 + i01*rk1b1;
        } else if (gi == k+1) {
            na  = i10*rka  + i11*rk1a;
            nb0 = i10*rkb0 + i11*rk1b0;
            nb1 = i10*rkb1 + i11*rk1b1;
        } else {
            na  = a  - (c0_*rka  + c1_*rk1a);
            nb0 = b0 - (c0_*rkb0 + c1_*rk1b0);
            nb1 = b1 - (c0_*rkb1 + c1_*rk1b1);
        }
        a = na; b0 = nb0; b1 = nb1;
    }
    sX[gi*16 + gj]     = b0;
    sX[gi*16 + gj + 8] = b1;

    // ---- 4: new_mean (held in regs; stored to sNM only after NC reads sX) ----
    float nm0, nm1;
    {
        float p0 = b0 * rin, p1 = b1 * rin;
        p0 += __shfl_xor(p0, 8);  p1 += __shfl_xor(p1, 8);
        p0 += __shfl_xor(p0, 16); p1 += __shfl_xor(p1, 16);
        p0 += __shfl_xor(p0, 32); p1 += __shfl_xor(p1, 32);
        nm0 = g_mean[(size_t)g*16 + gj]     + p0;
        nm1 = g_mean[(size_t)g*16 + gj + 8] + p1;
    }
    WSYNC();

    // ---- 5: NC = cov - CT^T @ X  (lane (r,c0): NC[r][c0..3]; cov from regs) ----
    {
        float4 n = cv;
        const float4 cta = *reinterpret_cast<const float4*>(sCTT + r*12);
        const float4 ctb = *reinterpret_cast<const float4*>(sCTT + r*12 + 4);
        const float ctt[8] = {cta.x,cta.y,cta.z,cta.w, ctb.x,ctb.y,ctb.z,ctb.w};
        #pragma unroll
        for (int m = 0; m < 8; ++m) {
            const float4 xq = *reinterpret_cast<const float4*>(sX + m*16 + c0);
            n.x -= ctt[m]*xq.x; n.y -= ctt[m]*xq.y; n.z -= ctt[m]*xq.z; n.w -= ctt[m]*xq.w;
        }
        *reinterpret_cast<float4*>(sNC + r*20 + c0) = n;
    }
    // now sX is dead -> store new_mean into overlapping sNM
    if (gi == 0) { sNM[gj] = nm0; sNM[gj + 8] = nm1; }
    WSYNC();

    // ---- F row r -> registers (pred_mean, T3, pred_cov) ----
    float4 fq[4];
    #pragma unroll
    for (int q = 0; q < 4; ++q)
        fq[q] = *reinterpret_cast<const float4*>(sF + r*20 + 4*q);

    // ---- 6: pred_mean[r] = dot(F row r, nm) (masked coalesced store) ----
    {
        float pm = 0.f;
        #pragma unroll
        for (int q = 0; q < 4; ++q) {
            const float4 nm = *reinterpret_cast<const float4*>(sNM + 4*q);
            pm += dot4(fq[q], nm);
        }
        if ((lane & 3) == 0) g_out[(size_t)g*16 + r] = pm;
    }

    // ---- 7: T3 = F@NC (NC sym): T3[r][c0..3] = dot(F row r, NC rows c0+x) ----
    {
        float t[4];
        #pragma unroll
        for (int x = 0; x < 4; ++x) {
            float acc = 0.f;
            #pragma unroll
            for (int q = 0; q < 4; ++q) {
                const float4 nc = *reinterpret_cast<const float4*>(sNC + (c0+x)*20 + 4*q);
                acc += dot4(fq[q], nc);
            }
            t[x] = acc;
        }
        *reinterpret_cast<float4*>(sT3 + r*20 + c0) = make_float4(t[0],t[1],t[2],t[3]);
    }
    WSYNC();

    // ---- 8: pred_cov[r][c0+x] (= pred_cov[c0+x][r] by symmetry)
    //         = dot(T3 row c0+x, F row r) + Q[r][c0+x]  -> coalesced float4 ----
    {
        const float4 qv = *reinterpret_cast<const float4*>(g_Q + (size_t)g*256 + lane*4);
        const float qq[4] = {qv.x, qv.y, qv.z, qv.w};
        float o[4];
        #pragma unroll
        for (int x = 0; x < 4; ++x) {
            float acc = qq[x];
            #pragma unroll
            for (int q = 0; q < 4; ++q) {
                const float4 t3 = *reinterpret_cast<const float4*>(sT3 + (c0+x)*20 + 4*q);
                acc += dot4(fq[q], t3);
            }
            o[x] = acc;
        }
        *reinterpret_cast<float4*>(g_out + (size_t)G*16 + (size_t)g*256 + lane*4) =
            make_float4(o[0], o[1], o[2], o[3]);
    }
}

extern "C" void kernel_launch(void* const* d_in, const int* in_sizes, int n_in,
                              void* d_out, int out_size, void* d_ws, size_t ws_size,
                              hipStream_t stream) {
    const float* g_in   = (const float*)d_in[0];
    const float* g_mean = (const float*)d_in[1];
    const float* g_cov  = (const float*)d_in[2];
    const float* g_H    = (const float*)d_in[3];
    const float* g_R    = (const float*)d_in[4];
    const float* g_F    = (const float*)d_in[5];
    const float* g_Q    = (const float*)d_in[6];
    float* out = (float*)d_out;
    const int G = in_sizes[2] / 256;   // cov is [G,16,16]
    kalman_kernel<<<G/4, 256, 0, stream>>>(g_in, g_mean, g_cov, g_H, g_R, g_F, g_Q, out, G);
}

// Round 5
// 183.395 us; speedup vs baseline: 1.2187x; 1.2187x over previous
//
#include <hip/hip_runtime.h>

// Batched Kalman step: G groups, S=16, M=8, fp32. One wave per group,
// 4 waves/block, wave-private LDS (no __syncthreads; same-wave DS is in-order).
//
// R5 = R2 structure (coalesced LDS staging, no spills) + R3/R4 wins:
//  - simple-form cov update NC = cov - CT^T X  (== Joseph in exact arithmetic)
//  - 2x2-blocked in-register Gauss-Jordan (4 serial shuffle stages)
//  - rcp + readlane pivots; shfl-xor new_mean reduce
//  - coalesced float4 pred_cov store via output symmetry
//  - LDS 3904 B/wave (T3 overlays dead sCT/sX) -> 15616 B/block
//  - NO min-waves launch bound (R4's ",8" forced VGPR=32 -> scratch spills,
//    seen as +350 MB phantom FETCH/WRITE traffic)

#define WSYNC() asm volatile("" ::: "memory")

__device__ __forceinline__ float lane_bcast(float v, int srclane) {
    return __int_as_float(__builtin_amdgcn_readlane(__float_as_int(v), srclane));
}
__device__ __forceinline__ float dot4(float4 a, float4 b) {
    return a.x*b.x + a.y*b.y + a.z*b.z + a.w*b.w;
}

__global__ __launch_bounds__(256) void kalman_kernel(
    const float* __restrict__ g_in,
    const float* __restrict__ g_mean,
    const float* __restrict__ g_cov,
    const float* __restrict__ g_H,
    const float* __restrict__ g_R,
    const float* __restrict__ g_F,
    const float* __restrict__ g_Q,
    float* __restrict__ g_out,
    int G)
{
    // per-wave LDS (floats), 976 total = 3904 B:
    //  sCov[16][20]@0    -> becomes NC in place (each lane rewrites own quad)
    //  sF  [16][20]@320
    //  sCT [8][20] @640 \ both dead after step 5 -> sT3[16][20]@640 overlays
    //  sX  [8][20] @800 /
    //  sNM [16]    @960
    __shared__ __align__(16) float smem[4][976];
    const int wv   = threadIdx.x >> 6;
    const int lane = threadIdx.x & 63;
    const int g    = (blockIdx.x << 2) | wv;
    float* const sm   = smem[wv];
    float* const sCov = sm;            // & NC
    float* const sF   = sm + 320;
    float* const sCT  = sm + 640;
    float* const sX   = sm + 800;
    float* const sT3  = sm + 640;      // overlays sCT+sX after step 5
    float* const sNM  = sm + 960;

    const int r  = lane >> 2;        // 0..15
    const int c0 = (lane & 3) << 2;  // 0,4,8,12
    const int gi = lane >> 3;        // 0..7
    const int gj = lane & 7;         // 0..7

    // ---- stage cov/F/H coalesced (contiguous lane*4 float4 first-touch) ----
    {
        const float4 cv = *reinterpret_cast<const float4*>(g_cov + (size_t)g*256 + lane*4);
        *reinterpret_cast<float4*>(sCov + r*20 + c0) = cv;
        const float4 fv = *reinterpret_cast<const float4*>(g_F + (size_t)g*256 + lane*4);
        *reinterpret_cast<float4*>(sF + r*20 + c0) = fv;
        if (lane < 32) {
            const float4 hv = *reinterpret_cast<const float4*>(g_H + (size_t)g*128 + lane*4);
            *reinterpret_cast<float4*>(sCT + (lane>>2)*20 + ((lane&3)<<2)) = hv;  // H parked in sCT area? no:
        }
    }
    // NOTE: H is parked in sT3/sCT region ONLY until CT overwrites it -> need
    // hq in registers before computing CT. (sCT doubles as H buffer.)
    WSYNC();

    // ---- H row gi -> registers (CT, Ssys, resid use it; dead before GJ) ----
    float4 hq[4];
    #pragma unroll
    for (int q = 0; q < 4; ++q)
        hq[q] = *reinterpret_cast<const float4*>(sCT + gi*20 + 4*q);
    WSYNC();

    // ---- 1: CT = H@cov (cov sym): lane (gi,gj) -> b0=CT[gi][gj], b1=CT[gi][gj+8] ----
    float b0 = 0.f, b1 = 0.f;
    #pragma unroll
    for (int q = 0; q < 4; ++q) {
        const float4 ca = *reinterpret_cast<const float4*>(sCov + gj*20 + 4*q);
        const float4 cb = *reinterpret_cast<const float4*>(sCov + (gj+8)*20 + 4*q);
        b0 += dot4(hq[q], ca);
        b1 += dot4(hq[q], cb);
    }
    WSYNC();   // all lanes done reading H from sCT region before overwriting
    sCT[gi*20 + gj]     = b0;
    sCT[gi*20 + gj + 8] = b1;
    WSYNC();

    // ---- 2: a = Ssys[gi][gj] = R + dot(H_gi, CT_gj);  resid rin ----
    float a = g_R[(size_t)g*64 + gi*8 + gj];
    #pragma unroll
    for (int q = 0; q < 4; ++q) {
        const float4 ct = *reinterpret_cast<const float4*>(sCT + gj*20 + 4*q);
        a += dot4(hq[q], ct);
    }
    float rin = g_in[(size_t)g*8 + gi];
    #pragma unroll
    for (int q = 0; q < 4; ++q) {
        const float4 m4 = *reinterpret_cast<const float4*>(g_mean + (size_t)g*16 + 4*q);
        rin -= dot4(hq[q], m4);
    }

    // ---- 3: 2x2-blocked Gauss-Jordan: [Ssys | CT] -> X = Ssys^-1 CT ----
    #pragma unroll
    for (int k = 0; k < 8; k += 2) {
        const int rk = k << 3, rk1 = (k+1) << 3;
        const float rka   = __shfl(a,  rk  | gj);
        const float rk1a  = __shfl(a,  rk1 | gj);
        const float rkb0  = __shfl(b0, rk  | gj);
        const float rk1b0 = __shfl(b0, rk1 | gj);
        const float rkb1  = __shfl(b1, rk  | gj);
        const float rk1b1 = __shfl(b1, rk1 | gj);
        const float ai0   = __shfl(a, (gi << 3) | k);
        const float ai1   = __shfl(a, (gi << 3) | (k+1));
        const float p00 = lane_bcast(a, rk  | k);
        const float p01 = lane_bcast(a, rk  | (k+1));
        const float p10 = lane_bcast(a, rk1 | k);
        const float p11 = lane_bcast(a, rk1 | (k+1));
        const float det  = p00*p11 - p01*p10;
        const float rdet = __builtin_amdgcn_rcpf(det);
        const float i00 =  p11*rdet, i01 = -p01*rdet;
        const float i10 = -p10*rdet, i11 =  p00*rdet;
        const float c0_ = ai0*i00 + ai1*i10;
        const float c1_ = ai0*i01 + ai1*i11;
        float na, nb0, nb1;
        if (gi == k) {
            na  = i00*rka  + i01*rk1a;
            nb0 = i00*rkb0 + i01*rk1b0;
            nb1 = i00*rkb1 + i01*rk1b1;
        } else if (gi == k+1) {
            na  = i10*rka  + i11*rk1a;
            nb0 = i10*rkb0 + i11*rk1b0;
            nb1 = i10*rkb1 + i11*rk1b1;
        } else {
            na  = a  - (c0_*rka  + c1_*rk1a);
            nb0 = b0 - (c0_*rkb0 + c1_*rk1b0);
            nb1 = b1 - (c0_*rkb1 + c1_*rk1b1);
        }
        a = na; b0 = nb0; b1 = nb1;
    }
    sX[gi*20 + gj]     = b0;
    sX[gi*20 + gj + 8] = b1;

    // ---- 4: new_mean[s] = mean[s] + sum_m X[m][s]*resid[m] (shfl-xor over gi) ----
    {
        float p0 = b0 * rin, p1 = b1 * rin;
        p0 += __shfl_xor(p0, 8);  p1 += __shfl_xor(p1, 8);
        p0 += __shfl_xor(p0, 16); p1 += __shfl_xor(p1, 16);
        p0 += __shfl_xor(p0, 32); p1 += __shfl_xor(p1, 32);
        if (gi == 0) {
            sNM[gj]     = g_mean[(size_t)g*16 + gj]     + p0;
            sNM[gj + 8] = g_mean[(size_t)g*16 + gj + 8] + p1;
        }
    }
    WSYNC();

    // ---- 5: NC[r][c0..3] = cov[r][c0..3] - sum_m CT[m][r] * X[m][c0..3]
    //         (in place in sCov: each lane reads+writes only its own quad) ----
    {
        float4 n = *reinterpret_cast<const float4*>(sCov + r*20 + c0);
        #pragma unroll
        for (int m = 0; m < 8; ++m) {
            const float ct = sCT[m*20 + r];                       // CT^T[r][m], broadcast x4
            const float4 xq = *reinterpret_cast<const float4*>(sX + m*20 + c0);
            n.x -= ct*xq.x; n.y -= ct*xq.y; n.z -= ct*xq.z; n.w -= ct*xq.w;
        }
        *reinterpret_cast<float4*>(sCov + r*20 + c0) = n;
    }
    WSYNC();

    // ---- F row r -> registers (pred_mean, T3, pred_cov) ----
    float4 fq[4];
    #pragma unroll
    for (int q = 0; q < 4; ++q)
        fq[q] = *reinterpret_cast<const float4*>(sF + r*20 + 4*q);

    // ---- 6: pred_mean[r] = dot(F_r, nm)  (masked coalesced store) ----
    {
        float pm = 0.f;
        #pragma unroll
        for (int q = 0; q < 4; ++q) {
            const float4 nm = *reinterpret_cast<const float4*>(sNM + 4*q);
            pm += dot4(fq[q], nm);
        }
        if ((lane & 3) == 0) g_out[(size_t)g*16 + r] = pm;
    }

    // ---- 7: T3[r][c0..3], T3[i][j] = dot(F_i, NC_j)  (NC sym) ----
    {
        float t[4];
        #pragma unroll
        for (int x = 0; x < 4; ++x) {
            float acc = 0.f;
            #pragma unroll
            for (int q = 0; q < 4; ++q) {
                const float4 nc = *reinterpret_cast<const float4*>(sCov + (c0+x)*20 + 4*q);
                acc += dot4(fq[q], nc);
            }
            t[x] = acc;
        }
        WSYNC();   // sCT/sX fully consumed before T3 overlays them
        *reinterpret_cast<float4*>(sT3 + r*20 + c0) = make_float4(t[0],t[1],t[2],t[3]);
    }
    WSYNC();

    // ---- 8: pred_cov[r][c0+x] (= [c0+x][r] by symmetry)
    //         = dot(T3_{c0+x}, F_r) + Q[r][c0+x]  -> coalesced float4 store ----
    {
        const float4 qv = *reinterpret_cast<const float4*>(g_Q + (size_t)g*256 + lane*4);
        const float qq[4] = {qv.x, qv.y, qv.z, qv.w};
        float o[4];
        #pragma unroll
        for (int x = 0; x < 4; ++x) {
            float acc = qq[x];
            #pragma unroll
            for (int q = 0; q < 4; ++q) {
                const float4 t3 = *reinterpret_cast<const float4*>(sT3 + (c0+x)*20 + 4*q);
                acc += dot4(fq[q], t3);
            }
            o[x] = acc;
        }
        *reinterpret_cast<float4*>(g_out + (size_t)G*16 + (size_t)g*256 + lane*4) =
            make_float4(o[0], o[1], o[2], o[3]);
    }
}

extern "C" void kernel_launch(void* const* d_in, const int* in_sizes, int n_in,
                              void* d_out, int out_size, void* d_ws, size_t ws_size,
                              hipStream_t stream) {
    const float* g_in   = (const float*)d_in[0];
    const float* g_mean = (const float*)d_in[1];
    const float* g_cov  = (const float*)d_in[2];
    const float* g_H    = (const float*)d_in[3];
    const float* g_R    = (const float*)d_in[4];
    const float* g_F    = (const float*)d_in[5];
    const float* g_Q    = (const float*)d_in[6];
    float* out = (float*)d_out;
    const int G = in_sizes[2] / 256;   // cov is [G,16,16]
    kalman_kernel<<<G/4, 256, 0, stream>>>(g_in, g_mean, g_cov, g_H, g_R, g_F, g_Q, out, G);
}

// Round 6
// 169.529 us; speedup vs baseline: 1.3183x; 1.0818x over previous
//
#include <hip/hip_runtime.h>

// Batched Kalman step: G groups, S=16, M=8, fp32. One wave per group,
// 4 waves/block, wave-private LDS (no __syncthreads; same-wave DS is in-order).
//
// R6 = R5 minus ~11 DS ops, minus ~30% VALU:
//  - H, F, mean, R, in, Q read straight from global (broadcast dwordx4,
//    issued ahead of long compute regions); LDS only for cov/CT/X/NC/T3/NM
//  - step 5 uses the cv register (no LDS re-read of cov quad)
//  - all dot accumulation in float2 ext-vectors -> v_pk_fma_f32
//  - LDS 2624 B/wave = 10496 B/block
//  - keep: 2x2-blocked in-register GJ, rcp+readlane pivots, shfl-xor nm
//    reduce, coalesced pred_cov float4 store via symmetry, no min-waves bound

typedef float v2f __attribute__((ext_vector_type(2)));

#define WSYNC() asm volatile("" ::: "memory")

__device__ __forceinline__ float lane_bcast(float v, int srclane) {
    return __int_as_float(__builtin_amdgcn_readlane(__float_as_int(v), srclane));
}
__device__ __forceinline__ v2f lo2(float4 v) { v2f r; r.x = v.x; r.y = v.y; return r; }
__device__ __forceinline__ v2f hi2(float4 v) { v2f r; r.x = v.z; r.y = v.w; return r; }

__global__ __launch_bounds__(256) void kalman_kernel(
    const float* __restrict__ g_in,
    const float* __restrict__ g_mean,
    const float* __restrict__ g_cov,
    const float* __restrict__ g_H,
    const float* __restrict__ g_R,
    const float* __restrict__ g_F,
    const float* __restrict__ g_Q,
    float* __restrict__ g_out,
    int G)
{
    // per-wave LDS (floats), 656 total = 2624 B:
    //  sCov[16][20]@0   cov -> NC in place
    //  sCT [8][20]@320 \ overlaid by sT3[16][20]@320 after step 5
    //  sX  [8][20]@480 /
    //  sNM [16]  @640
    __shared__ __align__(16) float smem[4][656];
    const int wv   = threadIdx.x >> 6;
    const int lane = threadIdx.x & 63;
    const int g    = (blockIdx.x << 2) | wv;
    float* const sm   = smem[wv];
    float* const sCov = sm;           // & NC
    float* const sCT  = sm + 320;
    float* const sX   = sm + 480;
    float* const sT3  = sm + 320;     // overlays sCT+sX after step 5
    float* const sNM  = sm + 640;

    const int r  = lane >> 2;        // 0..15
    const int c0 = (lane & 3) << 2;  // 0,4,8,12
    const int gi = lane >> 3;        // 0..7
    const int gj = lane & 7;         // 0..7

    // ---- hoisted global loads: cov quad (coalesced), H row gi (8-way bcast),
    //      R/in/mean (bcast) -- all independent, deep in flight ----
    const float4 cv = *reinterpret_cast<const float4*>(g_cov + (size_t)g*256 + lane*4);
    float4 hq[4];
    #pragma unroll
    for (int q = 0; q < 4; ++q)
        hq[q] = *reinterpret_cast<const float4*>(g_H + (size_t)g*128 + gi*16 + 4*q);
    float a   = g_R[(size_t)g*64 + gi*8 + gj];          // Ssys accumulator
    float rin = g_in[(size_t)g*8 + gi];                  // residual accumulator

    // resid = in - H@mean  (independent of LDS; mean regs die here)
    {
        v2f acc; acc.x = 0.f; acc.y = 0.f;
        #pragma unroll
        for (int q = 0; q < 4; ++q) {
            const float4 m4 = *reinterpret_cast<const float4*>(g_mean + (size_t)g*16 + 4*q);
            acc += lo2(hq[q]) * lo2(m4);
            acc += hi2(hq[q]) * hi2(m4);
        }
        rin -= acc.x + acc.y;
    }

    // ---- stage cov to LDS (coalesced first touch already done by cv) ----
    *reinterpret_cast<float4*>(sCov + r*20 + c0) = cv;
    WSYNC();

    // ---- 1: CT = H@cov (cov sym): lane (gi,gj) -> b0=CT[gi][gj], b1=CT[gi][gj+8] ----
    float b0, b1;
    {
        v2f a0; a0.x = 0.f; a0.y = 0.f;
        v2f a1; a1.x = 0.f; a1.y = 0.f;
        #pragma unroll
        for (int q = 0; q < 4; ++q) {
            const float4 ca = *reinterpret_cast<const float4*>(sCov + gj*20 + 4*q);
            const float4 cb = *reinterpret_cast<const float4*>(sCov + (gj+8)*20 + 4*q);
            a0 += lo2(hq[q]) * lo2(ca);
            a0 += hi2(hq[q]) * hi2(ca);
            a1 += lo2(hq[q]) * lo2(cb);
            a1 += hi2(hq[q]) * hi2(cb);
        }
        b0 = a0.x + a0.y;
        b1 = a1.x + a1.y;
    }
    sCT[gi*20 + gj]     = b0;
    sCT[gi*20 + gj + 8] = b1;
    WSYNC();

    // ---- 2: a = Ssys[gi][gj] = R + dot(H_gi, CT_gj) ----
    {
        v2f acc; acc.x = 0.f; acc.y = 0.f;
        #pragma unroll
        for (int q = 0; q < 4; ++q) {
            const float4 ct = *reinterpret_cast<const float4*>(sCT + gj*20 + 4*q);
            acc += lo2(hq[q]) * lo2(ct);
            acc += hi2(hq[q]) * hi2(ct);
        }
        a += acc.x + acc.y;
    }

    // ---- F row r -> registers (issued BEFORE the GJ serial chain so the
    //      ~400cy of shuffles covers the global latency; 4-way bcast) ----
    float4 fq[4];
    #pragma unroll
    for (int q = 0; q < 4; ++q)
        fq[q] = *reinterpret_cast<const float4*>(g_F + (size_t)g*256 + r*16 + 4*q);

    // ---- 3: 2x2-blocked Gauss-Jordan: [Ssys | CT] -> X = Ssys^-1 CT ----
    #pragma unroll
    for (int k = 0; k < 8; k += 2) {
        const int rk = k << 3, rk1 = (k+1) << 3;
        const float rka   = __shfl(a,  rk  | gj);
        const float rk1a  = __shfl(a,  rk1 | gj);
        const float rkb0  = __shfl(b0, rk  | gj);
        const float rk1b0 = __shfl(b0, rk1 | gj);
        const float rkb1  = __shfl(b1, rk  | gj);
        const float rk1b1 = __shfl(b1, rk1 | gj);
        const float ai0   = __shfl(a, (gi << 3) | k);
        const float ai1   = __shfl(a, (gi << 3) | (k+1));
        const float p00 = lane_bcast(a, rk  | k);
        const float p01 = lane_bcast(a, rk  | (k+1));
        const float p10 = lane_bcast(a, rk1 | k);
        const float p11 = lane_bcast(a, rk1 | (k+1));
        const float det  = p00*p11 - p01*p10;
        const float rdet = __builtin_amdgcn_rcpf(det);
        const float i00 =  p11*rdet, i01 = -p01*rdet;
        const float i10 = -p10*rdet, i11 =  p00*rdet;
        const float c0_ = ai0*i00 + ai1*i10;
        const float c1_ = ai0*i01 + ai1*i11;
        float na, nb0, nb1;
        if (gi == k) {
            na  = i00*rka  + i01*rk1a;
            nb0 = i00*rkb0 + i01*rk1b0;
            nb1 = i00*rkb1 + i01*rk1b1;
        } else if (gi == k+1) {
            na  = i10*rka  + i11*rk1a;
            nb0 = i10*rkb0 + i11*rk1b0;
            nb1 = i10*rkb1 + i11*rk1b1;
        } else {
            na  = a  - (c0_*rka  + c1_*rk1a);
            nb0 = b0 - (c0_*rkb0 + c1_*rk1b0);
            nb1 = b1 - (c0_*rkb1 + c1_*rk1b1);
        }
        a = na; b0 = nb0; b1 = nb1;
    }
    sX[gi*20 + gj]     = b0;
    sX[gi*20 + gj + 8] = b1;

    // ---- 4: new_mean[s] = mean[s] + sum_m X[m][s]*resid[m] (shfl-xor over gi) ----
    {
        float p0 = b0 * rin, p1 = b1 * rin;
        p0 += __shfl_xor(p0, 8);  p1 += __shfl_xor(p1, 8);
        p0 += __shfl_xor(p0, 16); p1 += __shfl_xor(p1, 16);
        p0 += __shfl_xor(p0, 32); p1 += __shfl_xor(p1, 32);
        if (gi == 0) {
            sNM[gj]     = g_mean[(size_t)g*16 + gj]     + p0;
            sNM[gj + 8] = g_mean[(size_t)g*16 + gj + 8] + p1;
        }
    }
    WSYNC();

    // ---- 5: NC[r][c0..3] = cov quad (cv regs) - sum_m CT[m][r] * X[m][c0..3] ----
    {
        v2f nlo = lo2(cv), nhi = hi2(cv);
        #pragma unroll
        for (int m = 0; m < 8; ++m) {
            const float ct = sCT[m*20 + r];                        // bcast x4
            const float4 xq = *reinterpret_cast<const float4*>(sX + m*20 + c0);
            v2f ctv; ctv.x = ct; ctv.y = ct;
            nlo -= ctv * lo2(xq);
            nhi -= ctv * hi2(xq);
        }
        float4 n; n.x = nlo.x; n.y = nlo.y; n.z = nhi.x; n.w = nhi.y;
        *reinterpret_cast<float4*>(sCov + r*20 + c0) = n;          // NC in place
    }
    WSYNC();

    // ---- 6: pred_mean[r] = dot(F_r, nm)  (masked coalesced store) ----
    {
        v2f acc; acc.x = 0.f; acc.y = 0.f;
        #pragma unroll
        for (int q = 0; q < 4; ++q) {
            const float4 nm = *reinterpret_cast<const float4*>(sNM + 4*q);
            acc += lo2(fq[q]) * lo2(nm);
            acc += hi2(fq[q]) * hi2(nm);
        }
        if ((lane & 3) == 0) g_out[(size_t)g*16 + r] = acc.x + acc.y;
    }

    // Q quad issued here (bcast-free coalesced), consumed in step 8
    const float4 qv = *reinterpret_cast<const float4*>(g_Q + (size_t)g*256 + lane*4);

    // ---- 7: T3[r][c0..3], T3[i][j] = dot(F_i, NC_j)  (NC sym) ----
    {
        float t[4];
        #pragma unroll
        for (int x = 0; x < 4; ++x) {
            v2f acc; acc.x = 0.f; acc.y = 0.f;
            #pragma unroll
            for (int q = 0; q < 4; ++q) {
                const float4 nc = *reinterpret_cast<const float4*>(sCov + (c0+x)*20 + 4*q);
                acc += lo2(fq[q]) * lo2(nc);
                acc += hi2(fq[q]) * hi2(nc);
            }
            t[x] = acc.x + acc.y;
        }
        WSYNC();   // sCT/sX fully consumed before T3 overlays them
        *reinterpret_cast<float4*>(sT3 + r*20 + c0) = make_float4(t[0],t[1],t[2],t[3]);
    }
    WSYNC();

    // ---- 8: pred_cov[r][c0+x] (= [c0+x][r] by symmetry)
    //         = dot(T3_{c0+x}, F_r) + Q[r][c0+x]  -> coalesced float4 store ----
    {
        const float qq[4] = {qv.x, qv.y, qv.z, qv.w};
        float o[4];
        #pragma unroll
        for (int x = 0; x < 4; ++x) {
            v2f acc; acc.x = 0.f; acc.y = 0.f;
            #pragma unroll
            for (int q = 0; q < 4; ++q) {
                const float4 t3 = *reinterpret_cast<const float4*>(sT3 + (c0+x)*20 + 4*q);
                acc += lo2(fq[q]) * lo2(t3);
                acc += hi2(fq[q]) * hi2(t3);
            }
            o[x] = qq[x] + acc.x + acc.y;
        }
        *reinterpret_cast<float4*>(g_out + (size_t)G*16 + (size_t)g*256 + lane*4) =
            make_float4(o[0], o[1], o[2], o[3]);
    }
}

extern "C" void kernel_launch(void* const* d_in, const int* in_sizes, int n_in,
                              void* d_out, int out_size, void* d_ws, size_t ws_size,
                              hipStream_t stream) {
    const float* g_in   = (const float*)d_in[0];
    const float* g_mean = (const float*)d_in[1];
    const float* g_cov  = (const float*)d_in[2];
    const float* g_H    = (const float*)d_in[3];
    const float* g_R    = (const float*)d_in[4];
    const float* g_F    = (const float*)d_in[5];
    const float* g_Q    = (const float*)d_in[6];
    float* out = (float*)d_out;
    const int G = in_sizes[2] / 256;   // cov is [G,16,16]
    kalman_kernel<<<G/4, 256, 0, stream>>>(g_in, g_mean, g_cov, g_H, g_R, g_F, g_Q, out, G);
}